// Round 5
// baseline (199.573 us; speedup 1.0000x reference)
//
#include <hip/hip_runtime.h>

// Problem constants (from setup_inputs): B=32, H=W=1024, N=96 boxes/batch.
#define BATCH 32
#define HDIM 1024
#define WDIM 1024
#define NBOX 96
#define THREADS 256
#define WAVES (THREADS / 64)          // 4
#define ROWS_PER_WAVE 4
#define ROWS_PER_BLOCK (WAVES * ROWS_PER_WAVE)   // 16 -> grid 2048, uniform work

// ---------------------------------------------------------------------------
// Round-4 post-mortem: scan time was ~52-55 us across bpermute/no-barrier/DPP
// variants -> compute path never mattered. Common factor: ~100+ VGPR puts us
// at 4 (or 2) waves/SIMD (occupancy steps at 64/128/256 VGPR), so the kernel
// runs latency-exposed at 2.6 TB/s (41% of achievable HBM).
// Round-5 design: <=64 VGPR for 8 waves/SIMD (32 waves/CU):
//   * no register prefetch (TLP hides latency, not ILP)
//   * boxes packed 2 VGPR each (x2-1 | x1>0-flag | x1-1; y2 | y1)
//   * DPP scan16 + readlane stitch (stitch constants live in SGPRs)
//   * __launch_bounds__(256, 8) pins the allocator to the 64-VGPR budget
// ---------------------------------------------------------------------------
__device__ __forceinline__ float dpp_scan16(float x) {
    int v;
    v = __builtin_amdgcn_update_dpp(0, __builtin_bit_cast(int, x), 0x111, 0xF, 0xF, true); // row_shr:1
    x += __builtin_bit_cast(float, v);
    v = __builtin_amdgcn_update_dpp(0, __builtin_bit_cast(int, x), 0x112, 0xF, 0xF, true); // row_shr:2
    x += __builtin_bit_cast(float, v);
    v = __builtin_amdgcn_update_dpp(0, __builtin_bit_cast(int, x), 0x114, 0xF, 0xF, true); // row_shr:4
    x += __builtin_bit_cast(float, v);
    v = __builtin_amdgcn_update_dpp(0, __builtin_bit_cast(int, x), 0x118, 0xF, 0xF, true); // row_shr:8
    x += __builtin_bit_cast(float, v);
    return x;
}
__device__ __forceinline__ float rl(float x, int l) {   // uniform readlane -> SGPR
    return __builtin_bit_cast(float, __builtin_amdgcn_readlane(__builtin_bit_cast(int, x), l));
}

// ---------------------------------------------------------------------------
// Kernel 0: zero the per-box accumulators in workspace (ws is poisoned 0xAA).
// ---------------------------------------------------------------------------
__global__ void zero_ws_kernel(float* __restrict__ ws) {
    int i = blockIdx.x * blockDim.x + threadIdx.x;
    if (i < BATCH * NBOX) ws[i] = 0.0f;
}

// ---------------------------------------------------------------------------
// Kernel 1: barrier-free per-wave row scan, low-VGPR / high-occupancy.
// Wave w owns rows row0+4w..+3; lane l owns columns 4l+256k (k=0..3).
// Lane l owns boxes l and l+64 (packed 2 VGPR each); per row <=2 segment
// lookups P[x2-1]-P[x1-1] from the wave-private LDS inclusive prefix.
// ---------------------------------------------------------------------------
__global__ __launch_bounds__(THREADS, 8) void row_scan_kernel(
    const float* __restrict__ img,
    const int* __restrict__ bboxes,
    float* __restrict__ ws_box) {

    __shared__ float P[WAVES][WDIM];   // 16 KB, wave-private segments

    const int t    = threadIdx.x;
    const int lane = t & 63;
    const int wave = t >> 6;
    const int g    = lane >> 4;        // DPP-row index 0..3

    const int blocks_per_batch = HDIM / ROWS_PER_BLOCK;   // 64
    const int b    = blockIdx.x / blocks_per_batch;
    const int row0 = (blockIdx.x % blocks_per_batch) * ROWS_PER_BLOCK
                   + wave * ROWS_PER_WAVE;

    // ---- per-lane owned boxes, packed to 2 VGPR each ----
    // xpack: [31:16]=x2-1, [15]=x1>0 flag, [9:0]=x1-1 (0 if x1==0)
    // ypack: [31:16]=y2, [15:0]=y1.  Invalid box -> both 0 (empty y-range).
    const int4* bbp = (const int4*)bboxes + b * NBOX;
    unsigned xpA = 0u, ypA = 0u, xpB = 0u, ypB = 0u;
    {
        int4 v = bbp[lane];
        int x1 = min(max(v.x, 0), WDIM), y1 = min(max(v.y, 0), WDIM);
        int x2 = min(max(v.z, 0), WDIM), y2 = min(max(v.w, 0), WDIM);
        if (x2 > x1) {
            xpA = ((unsigned)(x2 - 1) << 16)
                | (x1 > 0 ? (0x8000u | (unsigned)(x1 - 1)) : 0u);
            ypA = ((unsigned)y2 << 16) | (unsigned)y1;
        }
        if (lane < NBOX - 64) {
            v = bbp[64 + lane];
            x1 = min(max(v.x, 0), WDIM); y1 = min(max(v.y, 0), WDIM);
            x2 = min(max(v.z, 0), WDIM); y2 = min(max(v.w, 0), WDIM);
            if (x2 > x1) {
                xpB = ((unsigned)(x2 - 1) << 16)
                    | (x1 > 0 ? (0x8000u | (unsigned)(x1 - 1)) : 0u);
                ypB = ((unsigned)y2 << 16) | (unsigned)y1;
            }
        }
    }

    float accA = 0.0f, accB = 0.0f;
    const float* rbase = img + ((size_t)b * HDIM + row0) * WDIM;
    float* Pw = P[wave];

    #pragma unroll
    for (int r = 0; r < ROWS_PER_WAVE; ++r) {
        const float4* rp = (const float4*)(rbase + (size_t)r * WDIM);
        const float4 c0 = rp[lane];
        const float4 c1 = rp[lane +  64];
        const float4 c2 = rp[lane + 128];
        const float4 c3 = rp[lane + 192];

        // per-lane sequential sum of 4 elements, per chunk
        const float s0 = c0.x + c0.y + c0.z + c0.w;
        const float s1 = c1.x + c1.y + c1.z + c1.w;
        const float s2 = c2.x + c2.y + c2.z + c2.w;
        const float s3 = c3.x + c3.y + c3.z + c3.w;

        // 16-lane DPP scans (4 independent)
        const float q0 = dpp_scan16(s0);
        const float q1 = dpp_scan16(s1);
        const float q2 = dpp_scan16(s2);
        const float q3 = dpp_scan16(s3);

        // stitch constants -> SGPRs via readlane
        const float a0_0 = rl(q0, 15), a0_1 = rl(q0, 31), a0_2 = rl(q0, 47), a0_3 = rl(q0, 63);
        const float a1_0 = rl(q1, 15), a1_1 = rl(q1, 31), a1_2 = rl(q1, 47), a1_3 = rl(q1, 63);
        const float a2_0 = rl(q2, 15), a2_1 = rl(q2, 31), a2_2 = rl(q2, 47), a2_3 = rl(q2, 63);
        const float a3_0 = rl(q3, 15), a3_1 = rl(q3, 31), a3_2 = rl(q3, 47), a3_3 = rl(q3, 63);

        const float w0 = q0 + ((g >= 1) ? a0_0 : 0.0f) + ((g >= 2) ? a0_1 : 0.0f) + ((g >= 3) ? a0_2 : 0.0f);
        const float w1 = q1 + ((g >= 1) ? a1_0 : 0.0f) + ((g >= 2) ? a1_1 : 0.0f) + ((g >= 3) ? a1_2 : 0.0f);
        const float w2 = q2 + ((g >= 1) ? a2_0 : 0.0f) + ((g >= 2) ? a2_1 : 0.0f) + ((g >= 3) ? a2_2 : 0.0f);
        const float w3 = q3 + ((g >= 1) ? a3_0 : 0.0f) + ((g >= 2) ? a3_1 : 0.0f) + ((g >= 3) ? a3_2 : 0.0f);

        // chunk totals (SGPR) -> chunk base offsets
        const float t0 = a0_0 + a0_1 + a0_2 + a0_3;
        const float t1 = a1_0 + a1_1 + a1_2 + a1_3;
        const float t2 = a2_0 + a2_1 + a2_2 + a2_3;
        const float base1 = t0, base2 = t0 + t1, base3 = t0 + t1 + t2;

        // inclusive prefix per chunk; build+store immediately (tight liveness)
        {
            float4 p;
            p.w = w0;          p.z = p.w - c0.w; p.y = p.z - c0.z; p.x = p.y - c0.y;
            ((float4*)Pw)[lane] = p;
        }
        {
            float4 p;
            p.w = base1 + w1;  p.z = p.w - c1.w; p.y = p.z - c1.z; p.x = p.y - c1.y;
            ((float4*)Pw)[lane + 64] = p;
        }
        {
            float4 p;
            p.w = base2 + w2;  p.z = p.w - c2.w; p.y = p.z - c2.z; p.x = p.y - c2.y;
            ((float4*)Pw)[lane + 128] = p;
        }
        {
            float4 p;
            p.w = base3 + w3;  p.z = p.w - c3.w; p.y = p.z - c3.z; p.x = p.y - c3.y;
            ((float4*)Pw)[lane + 192] = p;
        }

        // ---- branchless box lookups (intra-wave LDS RAW; in-order DS pipe) ----
        const int y = row0 + r;
        {
            const float pR = Pw[xpA >> 16];
            float pL = Pw[xpA & 0x3FFu];
            pL = (xpA & 0x8000u) ? pL : 0.0f;
            const int y1 = (int)(ypA & 0xFFFFu), y2 = (int)(ypA >> 16);
            accA += ((y >= y1) && (y < y2)) ? (pR - pL) : 0.0f;
        }
        {
            const float pR = Pw[xpB >> 16];
            float pL = Pw[xpB & 0x3FFu];
            pL = (xpB & 0x8000u) ? pL : 0.0f;
            const int y1 = (int)(ypB & 0xFFFFu), y2 = (int)(ypB >> 16);
            accB += ((y >= y1) && (y < y2)) ? (pR - pL) : 0.0f;
        }
    }

    if (accA != 0.0f)                        atomicAdd(&ws_box[b * NBOX + lane],      accA);
    if (lane < NBOX - 64 && accB != 0.0f)    atomicAdd(&ws_box[b * NBOX + 64 + lane], accB);
}

// ---------------------------------------------------------------------------
// Kernel 2: loss = sum over boxes of relu(1 - (valid ? box_sum : 0)).
// Single block; 3072 boxes.
// ---------------------------------------------------------------------------
__global__ void finalize_kernel(const float* __restrict__ ws_box,
                                const int* __restrict__ bboxes,
                                float* __restrict__ out) {
    __shared__ float red[THREADS / 64];
    const int t = threadIdx.x;
    float local = 0.0f;
    for (int idx = t; idx < BATCH * NBOX; idx += THREADS) {
        const int4 bb = ((const int4*)bboxes)[idx];
        int x1 = min(max(bb.x, 0), WDIM);
        int y1 = min(max(bb.y, 0), WDIM);
        int x2 = min(max(bb.z, 0), WDIM);
        int y2 = min(max(bb.w, 0), WDIM);
        bool valid = (x2 > x1) && (y2 > y1);
        float s = valid ? ws_box[idx] : 0.0f;
        local += fmaxf(1.0f - s, 0.0f);
    }
    #pragma unroll
    for (int off = 32; off > 0; off >>= 1)
        local += __shfl_down(local, off, 64);
    if ((t & 63) == 0) red[t >> 6] = local;
    __syncthreads();
    if (t == 0) {
        float r = 0.0f;
        #pragma unroll
        for (int w = 0; w < THREADS / 64; ++w) r += red[w];
        out[0] = r;
    }
}

// ---------------------------------------------------------------------------
extern "C" void kernel_launch(void* const* d_in, const int* in_sizes, int n_in,
                              void* d_out, int out_size, void* d_ws, size_t ws_size,
                              hipStream_t stream) {
    const float* img    = (const float*)d_in[0];   // (32,1,1024,1024) fp32
    const int*   bboxes = (const int*)d_in[1];     // (32,96,4) int32
    float* out = (float*)d_out;                    // scalar
    float* ws_box = (float*)d_ws;                  // BATCH*NBOX accumulators

    zero_ws_kernel<<<(BATCH * NBOX + THREADS - 1) / THREADS, THREADS, 0, stream>>>(ws_box);

    const int nblocks = BATCH * HDIM / ROWS_PER_BLOCK;   // 2048 uniform blocks
    row_scan_kernel<<<nblocks, THREADS, 0, stream>>>(img, bboxes, ws_box);

    finalize_kernel<<<1, THREADS, 0, stream>>>(ws_box, bboxes, out);
}